// Round 17
// baseline (539.408 us; speedup 1.0000x reference)
//
#include <hip/hip_runtime.h>

#define DZ 64
#define DX 32
#define DS 16
#define TT 1024
#define NS 1024
#define SNZ (NS * DZ)
#define SNX (NS * DX)
#define SU  (NS * DS)

// ---- LDS layout (floats) ----
#define AW_B 0
#define C_B  (AW_B + DZ * (DZ + 1))      // 4160
#define B_B  (C_B + DZ * (DS + 1))       // 5248
#define SMEM_FLOATS (B_B + DX * (DZ + 1))   // 7328 floats = 29.3 KB
// runtime overlay ALIASES the AW staging region (anti-remat clobber):
#define ZR_O 0                 // raw z_t       [64]
#define RZ_O 64                // relu z_t      [64]
#define PM_O 128               // mu partials   [par2][wv4][64]
#define PX_O 640               // x  partials   [par2][wv4][32]  (ends at 895)

__device__ __forceinline__ float softplus_eps(float x) {
    // jax.nn.softplus = max(x,0) + log1p(exp(-|x|)); +1e-6
    return fmaxf(x, 0.f) + log1pf(expf(-fabsf(x))) + 1e-6f;
}

// LDS-only barrier (R16-proven safe): orders the partial exchange without
// draining in-flight global prefetch loads.
__device__ __forceinline__ void lds_barrier() {
    asm volatile("s_waitcnt lgkmcnt(0)" ::: "memory");
    __builtin_amdgcn_s_barrier();
}

// 4 waves per sim (k-quarters), 1024 blocks x 256 threads = 4096 waves
// -> 4 waves/SIMD. R14 structure with ONE change: weights are NAMED SCALARS,
// not arrays. R13/R14/R15 lesson: float Wrow[16] etc. were demoted wholesale
// (VGPR_Count=44, weights re-read every step, 786us) regardless of staging
// form or launch bounds. Named scalars leave no array object to demote.
__global__ __launch_bounds__(256, 2) void plrnn_q_kernel(
    const float* __restrict__ u,   // (T, N, 16)
    const float* __restrict__ z0,  // (N, 64)
    const float* __restrict__ nz,  // (T, N, 64)
    const float* __restrict__ nx,  // (T, N, 32)
    const float* __restrict__ AW,  // (64, 64)
    const float* __restrict__ Cm,  // (64, 16)
    const float* __restrict__ Bm,  // (32, 64)
    const float* __restrict__ Q,   // (64,)
    const float* __restrict__ R,   // (32,)
    float* __restrict__ zo,        // (T, N, 64)
    float* __restrict__ xo)        // (T, N, 32)
{
    const int tid  = threadIdx.x;
    const int lane = tid & 63;
    const int wvu  = tid >> 6;            // k-quarter 0..3 (plain, R12 pattern)
    const int p    = lane & 31;
    const int h    = lane >> 5;
    const int kx   = 16 * wvu + 8 * h;    // this lane's 8-k slice for x
    const int sim  = __builtin_amdgcn_readfirstlane((int)blockIdx.x);

    __shared__ float smem[SMEM_FLOATS];

    {   // one-time monolithic stage: AW 16/thr, C 4/thr, B 8/thr
        const int r = tid >> 2;
        const int c = (tid & 3) * 16;
        #pragma unroll
        for (int k = 0; k < 16; ++k) smem[AW_B + r * (DZ + 1) + c + k] = AW[r * DZ + c + k];
        const int cc = (tid & 3) * 4;
        #pragma unroll
        for (int k = 0; k < 4; ++k) smem[C_B + r * (DS + 1) + cc + k] = Cm[r * DS + cc + k];
        const int br = tid >> 3;
        const int bc = (tid & 7) * 8;
        #pragma unroll
        for (int k = 0; k < 8; ++k) smem[B_B + br * (DZ + 1) + bc + k] = Bm[br * DZ + bc + k];
    }
    __syncthreads();

    // ---- named-scalar weights (no arrays -> nothing to demote) ----
    const int wb = AW_B + lane * (DZ + 1);
    const int k0 = 16 * wvu;
#define LDW(i) (((k0 + (i)) == lane) ? 0.f : smem[wb + k0 + (i)])
    const float w0  = LDW(0),  w1  = LDW(1),  w2  = LDW(2),  w3  = LDW(3);
    const float w4  = LDW(4),  w5  = LDW(5),  w6  = LDW(6),  w7  = LDW(7);
    const float w8  = LDW(8),  w9  = LDW(9),  w10 = LDW(10), w11 = LDW(11);
    const float w12 = LDW(12), w13 = LDW(13), w14 = LDW(14), w15 = LDW(15);
#undef LDW
    const float Ad = smem[wb + lane];                  // diagonal
    const int cb = C_B + lane * (DS + 1) + 4 * wvu;
    const float c0 = smem[cb + 0], c1 = smem[cb + 1];
    const float c2 = smem[cb + 2], c3 = smem[cb + 3];
    const int bb = B_B + p * (DZ + 1) + kx;
    const float b0 = smem[bb + 0], b1 = smem[bb + 1];
    const float b2 = smem[bb + 2], b3 = smem[bb + 3];
    const float b4 = smem[bb + 4], b5 = smem[bb + 5];
    const float b6 = smem[bb + 6], b7 = smem[bb + 7];

    const float qv = softplus_eps(Q[lane]);
    const float rv = softplus_eps(R[p]);

    __syncthreads();   // staging reads done before overlay clobbers AW region

    float zl = z0[sim * DZ + lane];       // identical copy in all 4 waves

    const float* nzb = nz + sim * DZ;
    const float* nxb = nx + sim * DX;
    const float* ub  = u  + sim * DS + 4 * wvu;   // wave-uniform u slice
    float* zob = zo + sim * DZ;
    float* xob = xo + sim * DX;

    // prefetch depth 4, index-clamped (tail-safe)
    float nzp[4], nxp[4];
    float4 uqp[4];
    #pragma unroll
    for (int j = 0; j < 4; ++j) {
        nzp[j] = nzb[lane + j * SNZ];
        nxp[j] = nxb[p + j * SNX];
        uqp[j] = *(const float4*)(ub + j * SU);
    }

    for (int t0 = 0; t0 < TT; t0 += 4) {
        #pragma unroll
        for (int j = 0; j < 4; ++j) {
            const int t   = t0 + j;
            const int par = j & 1;
            const float  vnz = nzp[j];
            const float  vnx = nxp[j];
            const float4 uq  = uqp[j];

            // publish z_t (all waves write identical bits)
            smem[ZR_O + lane] = zl;
            smem[RZ_O + lane] = fmaxf(zl, 0.f);
            if (wvu == 0) zob[lane + t * SNZ] = zl;   // emit z_t (pre-update)

            // u-dot: wave-uniform float4
            float m0 = c0 * uq.x, m1 = c1 * uq.y;
            float m2 = c2 * uq.z, m3 = c3 * uq.w;

            // refill prefetch (clamped; tail values loaded but unused)
            {
                int tn = t + 4; tn = (tn < TT) ? tn : (TT - 1);
                nzp[j] = nzb[lane + tn * SNZ];
                nxp[j] = nxb[p + tn * SNX];
                uqp[j] = *(const float4*)(ub + tn * SU);
            }

            // W-quarter dot: 4 broadcast ds_read_b128 of relu(z_t)
            {
                const float4 z0v = *(const float4*)&smem[RZ_O + k0 + 0];
                const float4 z1v = *(const float4*)&smem[RZ_O + k0 + 4];
                const float4 z2v = *(const float4*)&smem[RZ_O + k0 + 8];
                const float4 z3v = *(const float4*)&smem[RZ_O + k0 + 12];
                m0 = fmaf(w0,  z0v.x, m0); m1 = fmaf(w1,  z0v.y, m1);
                m2 = fmaf(w2,  z0v.z, m2); m3 = fmaf(w3,  z0v.w, m3);
                m0 = fmaf(w4,  z1v.x, m0); m1 = fmaf(w5,  z1v.y, m1);
                m2 = fmaf(w6,  z1v.z, m2); m3 = fmaf(w7,  z1v.w, m3);
                m0 = fmaf(w8,  z2v.x, m0); m1 = fmaf(w9,  z2v.y, m1);
                m2 = fmaf(w10, z2v.z, m2); m3 = fmaf(w11, z2v.w, m3);
                m0 = fmaf(w12, z3v.x, m0); m1 = fmaf(w13, z3v.y, m1);
                m2 = fmaf(w14, z3v.z, m2); m3 = fmaf(w15, z3v.w, m3);
            }

            // x 8-k slice dot of raw z_t (2 reads), halves merged by shfl
            float xa0, xa1;
            {
                const float4 za = *(const float4*)&smem[ZR_O + kx];
                const float4 zb = *(const float4*)&smem[ZR_O + kx + 4];
                xa0 = b0 * za.x;            xa1 = b1 * za.y;
                xa0 = fmaf(b2, za.z, xa0);  xa1 = fmaf(b3, za.w, xa1);
                xa0 = fmaf(b4, zb.x, xa0);  xa1 = fmaf(b5, zb.y, xa1);
                xa0 = fmaf(b6, zb.z, xa0);  xa1 = fmaf(b7, zb.w, xa1);
            }
            float xpart = xa0 + xa1;
            xpart += __shfl_xor(xpart, 32);      // merge the two 8-k halves

            smem[PM_O + par * 256 + wvu * 64 + lane] = (m0 + m1) + (m2 + m3);
            if (lane < 32) smem[PX_O + par * 128 + wvu * 32 + p] = xpart;

            lds_barrier();   // the ONE barrier per step (LDS-only drain)

            // combine partials in FIXED order -> all waves' z' bit-identical
            const float q0 = smem[PM_O + par * 256 +   0 + lane];
            const float q1 = smem[PM_O + par * 256 +  64 + lane];
            const float q2 = smem[PM_O + par * 256 + 128 + lane];
            const float q3 = smem[PM_O + par * 256 + 192 + lane];

            if (wvu == 3 && lane < 32) {         // wave3 finishes + stores x_t
                const float xs = (smem[PX_O + par * 128 +  0 + p]
                                + smem[PX_O + par * 128 + 32 + p])
                               + (smem[PX_O + par * 128 + 64 + p]
                                + smem[PX_O + par * 128 + 96 + p]);
                xob[p + t * SNX] = fmaf(vnx, rv, xs);
            }

            // z_{t+1} = A_diag*z + (sum of 4 quarter-partials) + q*nz
            zl = fmaf(qv, vnz, fmaf(Ad, zl, (q0 + q1) + (q2 + q3)));
        }
    }
}

extern "C" void kernel_launch(void* const* d_in, const int* in_sizes, int n_in,
                              void* d_out, int out_size, void* d_ws, size_t ws_size,
                              hipStream_t stream) {
    const float* u_  = (const float*)d_in[0];
    const float* z0_ = (const float*)d_in[1];
    const float* nz_ = (const float*)d_in[2];
    const float* nx_ = (const float*)d_in[3];
    const float* AW_ = (const float*)d_in[4];
    const float* C_  = (const float*)d_in[5];
    const float* B_  = (const float*)d_in[6];
    const float* Q_  = (const float*)d_in[7];
    const float* R_  = (const float*)d_in[8];

    float* zo = (float*)d_out;                 // (T,N,64) first
    float* xo = zo + (size_t)TT * NS * DZ;     // then (T,N,32)

    hipLaunchKernelGGL(plrnn_q_kernel, dim3(NS), dim3(256), 0, stream,
                       u_, z0_, nz_, nx_, AW_, C_, B_, Q_, R_, zo, xo);
}